// Round 1
// 939.234 us; speedup vs baseline: 1.4470x; 1.4470x over previous
//
#include <hip/hip_runtime.h>
#include <math.h>

static constexpr int H = 496, W = 432, Bn = 2, Np = 16000;
static constexpr int HW = H * W;  // 214272

typedef __bf16 bf16x8 __attribute__((ext_vector_type(8)));
typedef float f32x16 __attribute__((ext_vector_type(16)));

// Gold-matching binning (R7-verified): multiply by f32-rounded reciprocal
// (RN_f32(1/0.16f) == 6.25f). DO NOT change to division.
__device__ inline void bin_xy(float px, float py, int& ix, int& iy) {
  ix = (int)floorf(px * 6.25f);
  iy = (int)floorf((py + 39.68f) * 6.25f);
  ix = min(max(ix, 0), W - 1);
  iy = min(max(iy, 0), H - 1);
}

// ---------------- Voxelization pass 1 ----------------
__global__ __launch_bounds__(256)
void count_kernel(const float* __restrict__ pts, int* __restrict__ cnt,
                  float* __restrict__ sums) {
  int p = blockIdx.x * blockDim.x + threadIdx.x;
  if (p >= Bn * Np) return;
  float px = pts[p * 4 + 0], py = pts[p * 4 + 1], pz = pts[p * 4 + 2];
  int b = p / Np;
  int ix, iy;
  bin_xy(px, py, ix, iy);
  int gid = b * HW + iy * W + ix;
  atomicAdd(&cnt[gid], 1);
  atomicAdd(&sums[3 * gid + 0], px);
  atomicAdd(&sums[3 * gid + 1], py);
  atomicAdd(&sums[3 * gid + 2], pz);
}

// ---------------- Voxelization pass 2: VFE + atomicMax scatter ----------------
__global__ __launch_bounds__(256)
void vfe_kernel(const float* __restrict__ pts, const int* __restrict__ cnt,
                const float* __restrict__ sums, const float* __restrict__ vw,
                const float* __restrict__ vs, const float* __restrict__ vt,
                float* __restrict__ out) {
  int tid = blockIdx.x * blockDim.x + threadIdx.x;
  if (tid >= Bn * Np * 64) return;
  int o = tid & 63;
  int p = tid >> 6;
  int b = p / Np;
  float px = pts[p * 4 + 0], py = pts[p * 4 + 1];
  float pz = pts[p * 4 + 2], pr = pts[p * 4 + 3];
  int ix, iy;
  bin_xy(px, py, ix, iy);
  int gid = b * HW + iy * W + ix;
  int n = cnt[gid];
  float denom = (float)max(n, 1);
  float mx = sums[3 * gid + 0] / denom;
  float my = sums[3 * gid + 1] / denom;
  float mz = sums[3 * gid + 2] / denom;
  float cx = (float)ix * 0.16f + 0.08f;
  float cy = (float)iy * 0.16f + (0.08f - 39.68f);
  float f[10] = {px, py, pz, pr, px - mx, py - my, pz - mz,
                 px - cx, py - cy, pz + 1.0f};
  const float* wr = vw + o * 10;
  float d = 0.f;
#pragma unroll
  for (int c = 0; c < 10; c++) d += f[c] * wr[c];
  float val = d * vs[o] + vt[o];
  val = fmaxf(val, 0.f);
  if (n < 32) val = fmaxf(val, fmaxf(vt[o], 0.f));
  unsigned int* dst = (unsigned int*)(out + (size_t)b * (84 * HW) +
                                      (size_t)(20 + o) * HW + (size_t)iy * W + ix);
  atomicMax(dst, __float_as_uint(val));
}

// ---------------- fp32 direct 3x3 conv (blocks 1 & 2 only) ----------------
template <int CI, int COT>
__global__ __launch_bounds__(256)
void conv3x3(const float* __restrict__ in, int in_bs, const float* __restrict__ w,
             const float* __restrict__ s, const float* __restrict__ t,
             float* __restrict__ out, int out_bs, int npix) {
  int pix = blockIdx.x * blockDim.x + threadIdx.x;
  if (pix >= npix) return;
  int b = pix / HW;
  int rem = pix - b * HW;
  int y = rem / W;
  int x = rem - y * W;
  int co0 = blockIdx.y * COT;
  const float* inb = in + (size_t)b * in_bs;

  int offs[9];
  bool okm[9];
#pragma unroll
  for (int ky = 0; ky < 3; ky++) {
    int yy = y + ky - 1;
    bool yok = (unsigned)yy < (unsigned)H;
#pragma unroll
    for (int kx = 0; kx < 3; kx++) {
      int xx = x + kx - 1;
      okm[ky * 3 + kx] = yok && ((unsigned)xx < (unsigned)W);
      offs[ky * 3 + kx] = yy * W + xx;
    }
  }
  float acc[COT];
#pragma unroll
  for (int i = 0; i < COT; i++) acc[i] = 0.f;
  for (int ci = 0; ci < CI; ci++) {
    const float* ip = inb + (size_t)ci * HW;
    float iv[9];
#pragma unroll
    for (int k = 0; k < 9; k++) iv[k] = okm[k] ? ip[offs[k]] : 0.f;
    const float* wp = w + ((size_t)co0 * CI + ci) * 9;
#pragma unroll
    for (int cg = 0; cg < COT; cg++) {
      const float* wc = wp + (size_t)cg * CI * 9;
#pragma unroll
      for (int k = 0; k < 9; k++) acc[cg] = fmaf(iv[k], wc[k], acc[cg]);
    }
  }
  float* ob = out + (size_t)b * out_bs + (size_t)rem;
#pragma unroll
  for (int cg = 0; cg < COT; cg++) {
    float v = acc[cg] * s[co0 + cg] + t[co0 + cg];
    ob[(size_t)(co0 + cg) * HW] = fmaxf(v, 0.f);
  }
}

// ---------------- weight prepack for block3 ----------------
// Fragment-ordered layout so a wave's B-frag load is ONE CONTIGUOUS 1KB block:
//   per (tap, kc[16-wide K step], ntile) a 512-elem block laid out as
//   [co32][khalf][8 elems]; lane l reads 16B at (l&31)*32B + (l>>5)*16B
//   -> 64 lanes cover exactly bytes [0,1024). (Old [co][tap][ci] layout made
//   each load a 32-line gather at stride 1152B: 50% line use, ~9K lines/blk.)
__global__ __launch_bounds__(256)
void prepack(const float* __restrict__ w0, const float* __restrict__ ws,
             __bf16* __restrict__ wt) {
  int idx = blockIdx.x * 256 + threadIdx.x;
  const int E0 = 64 * 144, EN = 64 * 576;
  if (idx < E0) {
    // layer0 CI=16: block = tp*2+nt (KC=1)
    int blk = idx >> 9, rem = idx & 511;
    int tp = blk >> 1, nt = blk & 1;
    int co = nt * 32 + (rem >> 4);
    int ci = rem & 15;  // = khalf*8 + e
    int ky = tp / 3, kx = tp - ky * 3;
    wt[idx] = (__bf16)w0[((co * 16 + ci) * 3 + ky) * 3 + kx];
  } else {
    int j = idx - E0;
    if (j >= 5 * EN) return;
    int n = j / EN, rr = j - n * EN;
    // CI=64: block = (tp*4+kc)*2+nt
    int blk = rr >> 9, rem = rr & 511;
    int tpkc = blk >> 1, nt = blk & 1;
    int tp = tpkc >> 2, kc = tpkc & 3;
    int co = nt * 32 + (rem >> 4);
    int ci = kc * 16 + (rem & 15);
    int ky = tp / 3, kx = tp - ky * 3;
    wt[idx] = (__bf16)ws[n * 36864 + ((co * 64 + ci) * 3 + ky) * 3 + kx];
  }
}

// ---------------- x2 (NCHW fp32, one batch) -> NHWC bf16 ----------------
// one thread per pixel: 16 coalesced f32 reads, one 32B contiguous store
__global__ __launch_bounds__(256)
void cvt_nhwc16(const float* __restrict__ x2b, __bf16* __restrict__ n16) {
  int p = blockIdx.x * 256 + threadIdx.x;
  if (p >= HW) return;
  __bf16 v[16];
#pragma unroll
  for (int ci = 0; ci < 16; ci++) v[ci] = (__bf16)x2b[(size_t)ci * HW + p];
  *(bf16x8*)(n16 + (size_t)p * 16) = *(bf16x8*)v;
  *(bf16x8*)(n16 + (size_t)p * 16 + 8) = *(bf16x8*)(v + 8);
}

// ---------------- MFMA implicit-GEMM 3x3 conv, NHWC bf16 in, one batch ---------
// wg = 256 thr (4 waves), tile 16x16 pixels x 64 co. Halo (18x18 x CI) staged
// once in LDS (serves all 9 taps). Wave wv owns tile rows 4wv..4wv+3 = 64 px,
// computed as 2 m-tiles x 2 n-tiles (4 f32x16 accs): each A-frag feeds 2 MFMAs
// and each B-frag feeds 2 MFMAs (halves per-MFMA load traffic vs 8x16 tile).
// B-frags come from the fragment-ordered weight pack: contiguous 1KB per load.
// FINAL: BN+ReLU then LDS-transpose (two 128-px chunks) -> coalesced NCHW fp32.
template <int CI, bool FINAL>
__global__ __launch_bounds__(256, 2)
void mconv(const __bf16* __restrict__ in, const __bf16* __restrict__ wt,
           const float* __restrict__ s, const float* __restrict__ t,
           __bf16* __restrict__ outb, float* __restrict__ outf) {
  constexpr int KC = CI / 16;
  constexpr int PADW = (CI == 64) ? 72 : 24;  // bf16 per-pixel stride; 16B-aligned
  constexpr int HALO_B = 324 * PADW * 2;      // 18x18 pixels
  constexpr int TRAN_B = FINAL ? 128 * 66 * 4 : 0;
  constexpr int SMEM_B = HALO_B > TRAN_B ? HALO_B : TRAN_B;  // 46656 for CI=64
  __shared__ __align__(16) char smem[SMEM_B];
  __bf16* hl = (__bf16*)smem;

  const int tid = threadIdx.x;
  const int ty = blockIdx.x / 27, tx = blockIdx.x - ty * 27;
  const int y0 = ty * 16, x0 = tx * 16;

  // stage halo: 18x18 pixels x CI channels (zeros outside image)
  constexpr int NCH = CI / 8;
  constexpr int TOT = 324 * NCH;
  for (int q = tid; q < TOT; q += 256) {
    int hp = q / NCH, c8 = q - hp * NCH;
    int hy = hp / 18, hx = hp - hy * 18;
    int gy = y0 - 1 + hy, gx = x0 - 1 + hx;
    int4 v = {0, 0, 0, 0};
    if ((unsigned)gy < (unsigned)H && (unsigned)gx < (unsigned)W)
      v = *(const int4*)(in + (size_t)(gy * W + gx) * CI + c8 * 8);
    *(int4*)(hl + hp * PADW + c8 * 8) = v;
  }
  __syncthreads();

  const int lane = tid & 63;
  const int wv = tid >> 6;
  const int col = lane & 31, half = lane >> 5;
  const int ly0 = 4 * wv + (col >> 4);  // A: m = col -> pixel row of m-tile 0
  const int lx = col & 15;

  f32x16 z = {0.f, 0.f, 0.f, 0.f, 0.f, 0.f, 0.f, 0.f,
              0.f, 0.f, 0.f, 0.f, 0.f, 0.f, 0.f, 0.f};
  f32x16 a00 = z, a01 = z, a10 = z, a11 = z;  // [mtile][ntile]

  const int laneoff = col * 16 + half * 8;

#pragma unroll
  for (int tp = 0; tp < 9; ++tp) {
    const __bf16* a0r = hl + ((ly0 + tp / 3) * 18 + lx + tp % 3) * PADW + half * 8;
    const __bf16* a1r = a0r + 2 * 18 * PADW;  // m-tile 1: +2 pixel rows
    const __bf16* bbase = wt + ((tp * KC) << 10) + laneoff;
#pragma unroll
    for (int kc = 0; kc < KC; ++kc) {
      bf16x8 af0 = *(const bf16x8*)(a0r + kc * 16);
      bf16x8 af1 = *(const bf16x8*)(a1r + kc * 16);
      const __bf16* bp = bbase + (kc << 10);
      bf16x8 b0 = *(const bf16x8*)(bp);        // ntile 0, contiguous 1KB/wave
      bf16x8 b1 = *(const bf16x8*)(bp + 512);  // ntile 1
      a00 = __builtin_amdgcn_mfma_f32_32x32x16_bf16(af0, b0, a00, 0, 0, 0);
      a01 = __builtin_amdgcn_mfma_f32_32x32x16_bf16(af0, b1, a01, 0, 0, 0);
      a10 = __builtin_amdgcn_mfma_f32_32x32x16_bf16(af1, b0, a10, 0, 0, 0);
      a11 = __builtin_amdgcn_mfma_f32_32x32x16_bf16(af1, b1, a11, 0, 0, 0);
    }
  }

  float s0 = s[col], t0v = t[col], s1 = s[col + 32], t1v = t[col + 32];
  if constexpr (!FINAL) {
#pragma unroll
    for (int r = 0; r < 16; ++r) {
      int row = (r & 3) + 8 * (r >> 2) + 4 * half;  // verified C/D map (m74/m101)
      int py = y0 + 4 * wv + (row >> 4);
      int px = x0 + (row & 15);
      size_t gp0 = (size_t)py * W + px;
      size_t gp1 = gp0 + (size_t)2 * W;  // m-tile 1
      outb[gp0 * 64 + col] = (__bf16)fmaxf(a00[r] * s0 + t0v, 0.f);
      outb[gp0 * 64 + col + 32] = (__bf16)fmaxf(a01[r] * s1 + t1v, 0.f);
      outb[gp1 * 64 + col] = (__bf16)fmaxf(a10[r] * s0 + t0v, 0.f);
      outb[gp1 * 64 + col + 32] = (__bf16)fmaxf(a11[r] * s1 + t1v, 0.f);
    }
  } else {
    float* tl = (float*)smem;
    // two 128-pixel chunks (waves {0,1} then {2,3}) so tl fits under halo size
    for (int h = 0; h < 2; ++h) {
      __syncthreads();  // h=0: halo reads done; h=1: chunk-0 stores done
      if ((wv >> 1) == h) {
        int wl = wv & 1;
#pragma unroll
        for (int r = 0; r < 16; ++r) {
          int row = (r & 3) + 8 * (r >> 2) + 4 * half;
          int lp0 = (4 * wl + (row >> 4)) * 16 + (row & 15);
          int lp1 = lp0 + 32;  // +2 pixel rows
          tl[lp0 * 66 + col] = fmaxf(a00[r] * s0 + t0v, 0.f);
          tl[lp0 * 66 + col + 32] = fmaxf(a01[r] * s1 + t1v, 0.f);
          tl[lp1 * 66 + col] = fmaxf(a10[r] * s0 + t0v, 0.f);
          tl[lp1 * 66 + col + 32] = fmaxf(a11[r] * s1 + t1v, 0.f);
        }
      }
      __syncthreads();
      for (int e = tid; e < 128 * 64; e += 256) {
        int co = e >> 7, mtl = e & 127;
        outf[(size_t)co * HW + (size_t)(y0 + h * 8 + (mtl >> 4)) * W +
             (x0 + (mtl & 15))] = tl[mtl * 66 + co];
      }
    }
  }
}

extern "C" void kernel_launch(void* const* d_in, const int* in_sizes, int n_in,
                              void* d_out, int out_size, void* d_ws, size_t ws_size,
                              hipStream_t stream) {
  const float* pts  = (const float*)d_in[0];
  const float* vw   = (const float*)d_in[1];
  const float* vs   = (const float*)d_in[2];
  const float* vt   = (const float*)d_in[3];
  const float* b1w0 = (const float*)d_in[4];
  const float* b1s0 = (const float*)d_in[5];
  const float* b1t0 = (const float*)d_in[6];
  const float* b1w  = (const float*)d_in[7];
  const float* b1s  = (const float*)d_in[8];
  const float* b1t  = (const float*)d_in[9];
  const float* b2w0 = (const float*)d_in[10];
  const float* b2s0 = (const float*)d_in[11];
  const float* b2t0 = (const float*)d_in[12];
  const float* b2w  = (const float*)d_in[13];
  const float* b2s  = (const float*)d_in[14];
  const float* b2t  = (const float*)d_in[15];
  const float* b3w0 = (const float*)d_in[16];
  const float* b3s0 = (const float*)d_in[17];
  const float* b3t0 = (const float*)d_in[18];
  const float* b3w  = (const float*)d_in[19];
  const float* b3s  = (const float*)d_in[20];
  const float* b3t  = (const float*)d_in[21];
  float* out = (float*)d_out;

  // ws usage (peak = 64*HW floats = 54.85 MB, EXACTLY the R7-proven footprint):
  //  phase vox:     cnt [0,2HW) ints + sums [2HW,8HW) floats
  //  phase blk1/2:  s16a [0,32HW) + s16b [32HW,64HW) floats
  //  phase blk3:    ppA bf16 [0, HW*64 elems = 27.4MB) ; Wt bf16 at byte 32*HW*4
  //                 (387 KB, written by prepack AFTER block2's last s16b use)
  float* wsf = (float*)d_ws;
  int* cnt = (int*)wsf;
  float* sums = wsf + (size_t)2 * HW;
  float* s16a = wsf;
  float* s16b = wsf + (size_t)32 * HW;
  __bf16* ppA = (__bf16*)d_ws;
  __bf16* Wt = (__bf16*)((char*)d_ws + (size_t)32 * HW * 4);

  hipMemsetAsync(out + (size_t)20 * HW, 0, (size_t)64 * HW * sizeof(float), stream);
  hipMemsetAsync(out + (size_t)(84 + 20) * HW, 0, (size_t)64 * HW * sizeof(float),
                 stream);
  hipMemsetAsync(cnt, 0, (size_t)8 * HW * sizeof(float), stream);

  count_kernel<<<(Bn * Np + 255) / 256, 256, 0, stream>>>(pts, cnt, sums);
  vfe_kernel<<<(Bn * Np * 64 + 255) / 256, 256, 0, stream>>>(pts, cnt, sums, vw, vs,
                                                             vt, out);

  const int g2 = (2 * HW + 255) / 256;
  dim3 blk(256);
  float* canvas = out + (size_t)20 * HW;

  // block1: 64->4, 3x(4->4); x1 -> out ch0..3
  conv3x3<64, 4><<<dim3(g2, 1), blk, 0, stream>>>(canvas, 84 * HW, b1w0, b1s0, b1t0,
                                                  s16a, 4 * HW, 2 * HW);
  conv3x3<4, 4><<<dim3(g2, 1), blk, 0, stream>>>(s16a, 4 * HW, b1w + 0 * 144,
                                                 b1s + 0, b1t + 0, s16b, 4 * HW,
                                                 2 * HW);
  conv3x3<4, 4><<<dim3(g2, 1), blk, 0, stream>>>(s16b, 4 * HW, b1w + 1 * 144,
                                                 b1s + 4, b1t + 4, s16a, 4 * HW,
                                                 2 * HW);
  conv3x3<4, 4><<<dim3(g2, 1), blk, 0, stream>>>(s16a, 4 * HW, b1w + 2 * 144,
                                                 b1s + 8, b1t + 8, out, 84 * HW,
                                                 2 * HW);

  // block2: 4->16, 5x(16->16); x2 -> out ch4..19
  conv3x3<4, 16><<<dim3(g2, 1), blk, 0, stream>>>(out, 84 * HW, b2w0, b2s0, b2t0,
                                                  s16a, 16 * HW, 2 * HW);
  conv3x3<16, 16><<<dim3(g2, 1), blk, 0, stream>>>(s16a, 16 * HW, b2w + 0 * 2304,
                                                   b2s + 0, b2t + 0, s16b, 16 * HW,
                                                   2 * HW);
  conv3x3<16, 16><<<dim3(g2, 1), blk, 0, stream>>>(s16b, 16 * HW, b2w + 1 * 2304,
                                                   b2s + 16, b2t + 16, s16a, 16 * HW,
                                                   2 * HW);
  conv3x3<16, 16><<<dim3(g2, 1), blk, 0, stream>>>(s16a, 16 * HW, b2w + 2 * 2304,
                                                   b2s + 32, b2t + 32, s16b, 16 * HW,
                                                   2 * HW);
  conv3x3<16, 16><<<dim3(g2, 1), blk, 0, stream>>>(s16b, 16 * HW, b2w + 3 * 2304,
                                                   b2s + 48, b2t + 48, s16a, 16 * HW,
                                                   2 * HW);
  conv3x3<16, 16><<<dim3(g2, 1), blk, 0, stream>>>(s16a, 16 * HW, b2w + 4 * 2304,
                                                   b2s + 64, b2t + 64, out + 4 * HW,
                                                   84 * HW, 2 * HW);

  // prepack AFTER block2 (s16a/s16b dead from here on)
  prepack<<<756, 256, 0, stream>>>(b3w0, b3w, Wt);

  // block3 via MFMA, per batch. pong_b = out ch20..83 of batch b reused as raw
  // bf16 storage (dead since block1-conv0; FINAL rewrites it as x3 fp32).
  dim3 mg(31 * 27, 1);  // 16x16-pixel tiles
  for (int b = 0; b < Bn; b++) {
    const float* x2b = out + (size_t)b * 84 * HW + (size_t)4 * HW;
    float* cb = out + (size_t)b * 84 * HW + (size_t)20 * HW;
    __bf16* pong = (__bf16*)cb;
    __bf16* n16 = (__bf16*)cb;  // n16 dead before pong first written (L1)
    cvt_nhwc16<<<(HW + 255) / 256, 256, 0, stream>>>(x2b, n16);
    mconv<16, false><<<mg, blk, 0, stream>>>(n16, Wt, b3s0, b3t0, ppA, nullptr);
    mconv<64, false><<<mg, blk, 0, stream>>>(ppA, Wt + 9216 + 0 * 36864, b3s + 0,
                                             b3t + 0, pong, nullptr);
    mconv<64, false><<<mg, blk, 0, stream>>>(pong, Wt + 9216 + 1 * 36864, b3s + 64,
                                             b3t + 64, ppA, nullptr);
    mconv<64, false><<<mg, blk, 0, stream>>>(ppA, Wt + 9216 + 2 * 36864, b3s + 128,
                                             b3t + 128, pong, nullptr);
    mconv<64, false><<<mg, blk, 0, stream>>>(pong, Wt + 9216 + 3 * 36864, b3s + 192,
                                             b3t + 192, ppA, nullptr);
    mconv<64, true><<<mg, blk, 0, stream>>>(ppA, Wt + 9216 + 4 * 36864, b3s + 256,
                                            b3t + 256, nullptr, cb);
  }
}

// Round 2
// 932.593 us; speedup vs baseline: 1.4573x; 1.0071x over previous
//
#include <hip/hip_runtime.h>
#include <math.h>

static constexpr int H = 496, W = 432, Bn = 2, Np = 16000;
static constexpr int HW = H * W;  // 214272

typedef __bf16 bf16x8 __attribute__((ext_vector_type(8)));
typedef float f32x16 __attribute__((ext_vector_type(16)));

// Gold-matching binning (R7-verified): multiply by f32-rounded reciprocal
// (RN_f32(1/0.16f) == 6.25f). DO NOT change to division.
__device__ inline void bin_xy(float px, float py, int& ix, int& iy) {
  ix = (int)floorf(px * 6.25f);
  iy = (int)floorf((py + 39.68f) * 6.25f);
  ix = min(max(ix, 0), W - 1);
  iy = min(max(iy, 0), H - 1);
}

// ---------------- Voxelization pass 1 ----------------
__global__ __launch_bounds__(256)
void count_kernel(const float* __restrict__ pts, int* __restrict__ cnt,
                  float* __restrict__ sums) {
  int p = blockIdx.x * blockDim.x + threadIdx.x;
  if (p >= Bn * Np) return;
  float px = pts[p * 4 + 0], py = pts[p * 4 + 1], pz = pts[p * 4 + 2];
  int b = p / Np;
  int ix, iy;
  bin_xy(px, py, ix, iy);
  int gid = b * HW + iy * W + ix;
  atomicAdd(&cnt[gid], 1);
  atomicAdd(&sums[3 * gid + 0], px);
  atomicAdd(&sums[3 * gid + 1], py);
  atomicAdd(&sums[3 * gid + 2], pz);
}

// ---------------- Voxelization pass 2: VFE + atomicMax scatter ----------------
__global__ __launch_bounds__(256)
void vfe_kernel(const float* __restrict__ pts, const int* __restrict__ cnt,
                const float* __restrict__ sums, const float* __restrict__ vw,
                const float* __restrict__ vs, const float* __restrict__ vt,
                float* __restrict__ out) {
  int tid = blockIdx.x * blockDim.x + threadIdx.x;
  if (tid >= Bn * Np * 64) return;
  int o = tid & 63;
  int p = tid >> 6;
  int b = p / Np;
  float px = pts[p * 4 + 0], py = pts[p * 4 + 1];
  float pz = pts[p * 4 + 2], pr = pts[p * 4 + 3];
  int ix, iy;
  bin_xy(px, py, ix, iy);
  int gid = b * HW + iy * W + ix;
  int n = cnt[gid];
  float denom = (float)max(n, 1);
  float mx = sums[3 * gid + 0] / denom;
  float my = sums[3 * gid + 1] / denom;
  float mz = sums[3 * gid + 2] / denom;
  float cx = (float)ix * 0.16f + 0.08f;
  float cy = (float)iy * 0.16f + (0.08f - 39.68f);
  float f[10] = {px, py, pz, pr, px - mx, py - my, pz - mz,
                 px - cx, py - cy, pz + 1.0f};
  const float* wr = vw + o * 10;
  float d = 0.f;
#pragma unroll
  for (int c = 0; c < 10; c++) d += f[c] * wr[c];
  float val = d * vs[o] + vt[o];
  val = fmaxf(val, 0.f);
  if (n < 32) val = fmaxf(val, fmaxf(vt[o], 0.f));
  unsigned int* dst = (unsigned int*)(out + (size_t)b * (84 * HW) +
                                      (size_t)(20 + o) * HW + (size_t)iy * W + ix);
  atomicMax(dst, __float_as_uint(val));
}

// ---------------- fp32 direct 3x3 conv (blocks 1 & 2 only) ----------------
template <int CI, int COT>
__global__ __launch_bounds__(256)
void conv3x3(const float* __restrict__ in, int in_bs, const float* __restrict__ w,
             const float* __restrict__ s, const float* __restrict__ t,
             float* __restrict__ out, int out_bs, int npix) {
  int pix = blockIdx.x * blockDim.x + threadIdx.x;
  if (pix >= npix) return;
  int b = pix / HW;
  int rem = pix - b * HW;
  int y = rem / W;
  int x = rem - y * W;
  int co0 = blockIdx.y * COT;
  const float* inb = in + (size_t)b * in_bs;

  int offs[9];
  bool okm[9];
#pragma unroll
  for (int ky = 0; ky < 3; ky++) {
    int yy = y + ky - 1;
    bool yok = (unsigned)yy < (unsigned)H;
#pragma unroll
    for (int kx = 0; kx < 3; kx++) {
      int xx = x + kx - 1;
      okm[ky * 3 + kx] = yok && ((unsigned)xx < (unsigned)W);
      offs[ky * 3 + kx] = yy * W + xx;
    }
  }
  float acc[COT];
#pragma unroll
  for (int i = 0; i < COT; i++) acc[i] = 0.f;
  for (int ci = 0; ci < CI; ci++) {
    const float* ip = inb + (size_t)ci * HW;
    float iv[9];
#pragma unroll
    for (int k = 0; k < 9; k++) iv[k] = okm[k] ? ip[offs[k]] : 0.f;
    const float* wp = w + ((size_t)co0 * CI + ci) * 9;
#pragma unroll
    for (int cg = 0; cg < COT; cg++) {
      const float* wc = wp + (size_t)cg * CI * 9;
#pragma unroll
      for (int k = 0; k < 9; k++) acc[cg] = fmaf(iv[k], wc[k], acc[cg]);
    }
  }
  float* ob = out + (size_t)b * out_bs + (size_t)rem;
#pragma unroll
  for (int cg = 0; cg < COT; cg++) {
    float v = acc[cg] * s[co0 + cg] + t[co0 + cg];
    ob[(size_t)(co0 + cg) * HW] = fmaxf(v, 0.f);
  }
}

// ---------------- weight prepack for block3 ----------------
// Fragment-ordered layout so a wave's B-frag load is ONE CONTIGUOUS 1KB block:
//   per (tap, kc[16-wide K step], ntile) a 512-elem block laid out as
//   [co32][khalf][8 elems]; lane l reads 16B at (l&31)*32B + (l>>5)*16B
//   -> 64 lanes cover exactly bytes [0,1024).
__global__ __launch_bounds__(256)
void prepack(const float* __restrict__ w0, const float* __restrict__ ws,
             __bf16* __restrict__ wt) {
  int idx = blockIdx.x * 256 + threadIdx.x;
  const int E0 = 64 * 144, EN = 64 * 576;
  if (idx < E0) {
    // layer0 CI=16: block = tp*2+nt (KC=1)
    int blk = idx >> 9, rem = idx & 511;
    int tp = blk >> 1, nt = blk & 1;
    int co = nt * 32 + (rem >> 4);
    int ci = rem & 15;  // = khalf*8 + e
    int ky = tp / 3, kx = tp - ky * 3;
    wt[idx] = (__bf16)w0[((co * 16 + ci) * 3 + ky) * 3 + kx];
  } else {
    int j = idx - E0;
    if (j >= 5 * EN) return;
    int n = j / EN, rr = j - n * EN;
    // CI=64: block = (tp*4+kc)*2+nt
    int blk = rr >> 9, rem = rr & 511;
    int tpkc = blk >> 1, nt = blk & 1;
    int tp = tpkc >> 2, kc = tpkc & 3;
    int co = nt * 32 + (rem >> 4);
    int ci = kc * 16 + (rem & 15);
    int ky = tp / 3, kx = tp - ky * 3;
    wt[idx] = (__bf16)ws[n * 36864 + ((co * 64 + ci) * 3 + ky) * 3 + kx];
  }
}

// ---------------- x2 (NCHW fp32, one batch) -> NHWC bf16 ----------------
// one thread per pixel: 16 coalesced f32 reads, one 32B contiguous store
__global__ __launch_bounds__(256)
void cvt_nhwc16(const float* __restrict__ x2b, __bf16* __restrict__ n16) {
  int p = blockIdx.x * 256 + threadIdx.x;
  if (p >= HW) return;
  __bf16 v[16];
#pragma unroll
  for (int ci = 0; ci < 16; ci++) v[ci] = (__bf16)x2b[(size_t)ci * HW + p];
  *(bf16x8*)(n16 + (size_t)p * 16) = *(bf16x8*)v;
  *(bf16x8*)(n16 + (size_t)p * 16 + 8) = *(bf16x8*)(v + 8);
}

// ---------------- MFMA implicit-GEMM 3x3 conv, NHWC bf16 in, one batch ---------
// wg = 256 thr (4 waves), tile 16x16 pixels x 64 co. Halo (18x18 x CI) staged
// once in LDS. Wave wv owns 64 px as 2 m-tiles x 2 n-tiles (4 f32x16 accs).
// R2: explicit TAP-LEVEL SOFTWARE PIPELINE — fragments for tap tp+1 (8 ds_read
// + 8 global per wave) are issued into the alternate register set BEFORE the
// 16 MFMAs of tap tp, guaranteeing >=128 cycles of MFMA cover per load. The
// previous single-set loop ran unpipelined (every load stalled full latency:
// ~41K observed cycles/block vs ~1.2K MFMA). Accumulation order is unchanged
// (tp-major, kc-minor, identical operand pairing) -> bitwise-identical output.
// FINAL: BN+ReLU then LDS-transpose (two 128-px chunks) -> coalesced NCHW fp32.
template <int CI, bool FINAL>
__global__ __launch_bounds__(256, 2)
void mconv(const __bf16* __restrict__ in, const __bf16* __restrict__ wt,
           const float* __restrict__ s, const float* __restrict__ t,
           __bf16* __restrict__ outb, float* __restrict__ outf) {
  constexpr int KC = CI / 16;
  constexpr int PADW = (CI == 64) ? 72 : 24;  // bf16 per-pixel stride; 16B-aligned
  constexpr int HALO_B = 324 * PADW * 2;      // 18x18 pixels
  constexpr int TRAN_B = FINAL ? 128 * 66 * 4 : 0;
  constexpr int SMEM_B = HALO_B > TRAN_B ? HALO_B : TRAN_B;  // 46656 for CI=64
  __shared__ __align__(16) char smem[SMEM_B];
  __bf16* hl = (__bf16*)smem;

  const int tid = threadIdx.x;
  const int ty = blockIdx.x / 27, tx = blockIdx.x - ty * 27;
  const int y0 = ty * 16, x0 = tx * 16;

  // stage halo: 18x18 pixels x CI channels (zeros outside image)
  constexpr int NCH = CI / 8;
  constexpr int TOT = 324 * NCH;
  for (int q = tid; q < TOT; q += 256) {
    int hp = q / NCH, c8 = q - hp * NCH;
    int hy = hp / 18, hx = hp - hy * 18;
    int gy = y0 - 1 + hy, gx = x0 - 1 + hx;
    int4 v = {0, 0, 0, 0};
    if ((unsigned)gy < (unsigned)H && (unsigned)gx < (unsigned)W)
      v = *(const int4*)(in + (size_t)(gy * W + gx) * CI + c8 * 8);
    *(int4*)(hl + hp * PADW + c8 * 8) = v;
  }
  __syncthreads();

  const int lane = tid & 63;
  const int wv = tid >> 6;
  const int col = lane & 31, half = lane >> 5;
  const int ly0 = 4 * wv + (col >> 4);  // A: m = col -> pixel row of m-tile 0
  const int lx = col & 15;

  f32x16 z = {0.f, 0.f, 0.f, 0.f, 0.f, 0.f, 0.f, 0.f,
              0.f, 0.f, 0.f, 0.f, 0.f, 0.f, 0.f, 0.f};
  f32x16 a00 = z, a01 = z, a10 = z, a11 = z;  // [mtile][ntile]

  const int laneoff = col * 16 + half * 8;
  const __bf16* wbase = wt + laneoff;

  // double-buffered fragment sets (all indices compile-time after unroll)
  bf16x8 Af0[2][KC], Af1[2][KC], Bf0[2][KC], Bf1[2][KC];

  auto LOADTAP = [&](int tp, int buf) {
    const __bf16* a0r = hl + ((ly0 + tp / 3) * 18 + lx + tp % 3) * PADW + half * 8;
    const __bf16* a1r = a0r + 2 * 18 * PADW;  // m-tile 1: +2 pixel rows
    const __bf16* bb = wbase + ((tp * KC) << 10);
#pragma unroll
    for (int kc = 0; kc < KC; ++kc) {
      Af0[buf][kc] = *(const bf16x8*)(a0r + kc * 16);
      Af1[buf][kc] = *(const bf16x8*)(a1r + kc * 16);
      Bf0[buf][kc] = *(const bf16x8*)(bb + (kc << 10));
      Bf1[buf][kc] = *(const bf16x8*)(bb + (kc << 10) + 512);
    }
  };

  LOADTAP(0, 0);
#pragma unroll
  for (int tp = 0; tp < 9; ++tp) {
    const int cur = tp & 1;
    if (tp < 8) LOADTAP(tp + 1, cur ^ 1);  // prefetch next tap under MFMAs
#pragma unroll
    for (int kc = 0; kc < KC; ++kc) {
      a00 = __builtin_amdgcn_mfma_f32_32x32x16_bf16(Af0[cur][kc], Bf0[cur][kc],
                                                    a00, 0, 0, 0);
      a01 = __builtin_amdgcn_mfma_f32_32x32x16_bf16(Af0[cur][kc], Bf1[cur][kc],
                                                    a01, 0, 0, 0);
      a10 = __builtin_amdgcn_mfma_f32_32x32x16_bf16(Af1[cur][kc], Bf0[cur][kc],
                                                    a10, 0, 0, 0);
      a11 = __builtin_amdgcn_mfma_f32_32x32x16_bf16(Af1[cur][kc], Bf1[cur][kc],
                                                    a11, 0, 0, 0);
    }
  }

  float s0 = s[col], t0v = t[col], s1 = s[col + 32], t1v = t[col + 32];
  if constexpr (!FINAL) {
#pragma unroll
    for (int r = 0; r < 16; ++r) {
      int row = (r & 3) + 8 * (r >> 2) + 4 * half;  // verified C/D map (m74/m101)
      int py = y0 + 4 * wv + (row >> 4);
      int px = x0 + (row & 15);
      size_t gp0 = (size_t)py * W + px;
      size_t gp1 = gp0 + (size_t)2 * W;  // m-tile 1
      outb[gp0 * 64 + col] = (__bf16)fmaxf(a00[r] * s0 + t0v, 0.f);
      outb[gp0 * 64 + col + 32] = (__bf16)fmaxf(a01[r] * s1 + t1v, 0.f);
      outb[gp1 * 64 + col] = (__bf16)fmaxf(a10[r] * s0 + t0v, 0.f);
      outb[gp1 * 64 + col + 32] = (__bf16)fmaxf(a11[r] * s1 + t1v, 0.f);
    }
  } else {
    float* tl = (float*)smem;
    // two 128-pixel chunks (waves {0,1} then {2,3}) so tl fits under halo size
    for (int h = 0; h < 2; ++h) {
      __syncthreads();  // h=0: halo reads done; h=1: chunk-0 stores done
      if ((wv >> 1) == h) {
        int wl = wv & 1;
#pragma unroll
        for (int r = 0; r < 16; ++r) {
          int row = (r & 3) + 8 * (r >> 2) + 4 * half;
          int lp0 = (4 * wl + (row >> 4)) * 16 + (row & 15);
          int lp1 = lp0 + 32;  // +2 pixel rows
          tl[lp0 * 66 + col] = fmaxf(a00[r] * s0 + t0v, 0.f);
          tl[lp0 * 66 + col + 32] = fmaxf(a01[r] * s1 + t1v, 0.f);
          tl[lp1 * 66 + col] = fmaxf(a10[r] * s0 + t0v, 0.f);
          tl[lp1 * 66 + col + 32] = fmaxf(a11[r] * s1 + t1v, 0.f);
        }
      }
      __syncthreads();
      for (int e = tid; e < 128 * 64; e += 256) {
        int co = e >> 7, mtl = e & 127;
        outf[(size_t)co * HW + (size_t)(y0 + h * 8 + (mtl >> 4)) * W +
             (x0 + (mtl & 15))] = tl[mtl * 66 + co];
      }
    }
  }
}

extern "C" void kernel_launch(void* const* d_in, const int* in_sizes, int n_in,
                              void* d_out, int out_size, void* d_ws, size_t ws_size,
                              hipStream_t stream) {
  const float* pts  = (const float*)d_in[0];
  const float* vw   = (const float*)d_in[1];
  const float* vs   = (const float*)d_in[2];
  const float* vt   = (const float*)d_in[3];
  const float* b1w0 = (const float*)d_in[4];
  const float* b1s0 = (const float*)d_in[5];
  const float* b1t0 = (const float*)d_in[6];
  const float* b1w  = (const float*)d_in[7];
  const float* b1s  = (const float*)d_in[8];
  const float* b1t  = (const float*)d_in[9];
  const float* b2w0 = (const float*)d_in[10];
  const float* b2s0 = (const float*)d_in[11];
  const float* b2t0 = (const float*)d_in[12];
  const float* b2w  = (const float*)d_in[13];
  const float* b2s  = (const float*)d_in[14];
  const float* b2t  = (const float*)d_in[15];
  const float* b3w0 = (const float*)d_in[16];
  const float* b3s0 = (const float*)d_in[17];
  const float* b3t0 = (const float*)d_in[18];
  const float* b3w  = (const float*)d_in[19];
  const float* b3s  = (const float*)d_in[20];
  const float* b3t  = (const float*)d_in[21];
  float* out = (float*)d_out;

  // ws usage (peak = 64*HW floats = 54.85 MB, EXACTLY the R7-proven footprint):
  //  phase vox:     cnt [0,2HW) ints + sums [2HW,8HW) floats
  //  phase blk1/2:  s16a [0,32HW) + s16b [32HW,64HW) floats
  //  phase blk3:    ppA bf16 [0, HW*64 elems = 27.4MB) ; Wt bf16 at byte 32*HW*4
  //                 (387 KB, written by prepack AFTER block2's last s16b use)
  float* wsf = (float*)d_ws;
  int* cnt = (int*)wsf;
  float* sums = wsf + (size_t)2 * HW;
  float* s16a = wsf;
  float* s16b = wsf + (size_t)32 * HW;
  __bf16* ppA = (__bf16*)d_ws;
  __bf16* Wt = (__bf16*)((char*)d_ws + (size_t)32 * HW * 4);

  hipMemsetAsync(out + (size_t)20 * HW, 0, (size_t)64 * HW * sizeof(float), stream);
  hipMemsetAsync(out + (size_t)(84 + 20) * HW, 0, (size_t)64 * HW * sizeof(float),
                 stream);
  hipMemsetAsync(cnt, 0, (size_t)8 * HW * sizeof(float), stream);

  count_kernel<<<(Bn * Np + 255) / 256, 256, 0, stream>>>(pts, cnt, sums);
  vfe_kernel<<<(Bn * Np * 64 + 255) / 256, 256, 0, stream>>>(pts, cnt, sums, vw, vs,
                                                             vt, out);

  const int g2 = (2 * HW + 255) / 256;
  dim3 blk(256);
  float* canvas = out + (size_t)20 * HW;

  // block1: 64->4, 3x(4->4); x1 -> out ch0..3
  conv3x3<64, 4><<<dim3(g2, 1), blk, 0, stream>>>(canvas, 84 * HW, b1w0, b1s0, b1t0,
                                                  s16a, 4 * HW, 2 * HW);
  conv3x3<4, 4><<<dim3(g2, 1), blk, 0, stream>>>(s16a, 4 * HW, b1w + 0 * 144,
                                                 b1s + 0, b1t + 0, s16b, 4 * HW,
                                                 2 * HW);
  conv3x3<4, 4><<<dim3(g2, 1), blk, 0, stream>>>(s16b, 4 * HW, b1w + 1 * 144,
                                                 b1s + 4, b1t + 4, s16a, 4 * HW,
                                                 2 * HW);
  conv3x3<4, 4><<<dim3(g2, 1), blk, 0, stream>>>(s16a, 4 * HW, b1w + 2 * 144,
                                                 b1s + 8, b1t + 8, out, 84 * HW,
                                                 2 * HW);

  // block2: 4->16, 5x(16->16); x2 -> out ch4..19
  conv3x3<4, 16><<<dim3(g2, 1), blk, 0, stream>>>(out, 84 * HW, b2w0, b2s0, b2t0,
                                                  s16a, 16 * HW, 2 * HW);
  conv3x3<16, 16><<<dim3(g2, 1), blk, 0, stream>>>(s16a, 16 * HW, b2w + 0 * 2304,
                                                   b2s + 0, b2t + 0, s16b, 16 * HW,
                                                   2 * HW);
  conv3x3<16, 16><<<dim3(g2, 1), blk, 0, stream>>>(s16b, 16 * HW, b2w + 1 * 2304,
                                                   b2s + 16, b2t + 16, s16a, 16 * HW,
                                                   2 * HW);
  conv3x3<16, 16><<<dim3(g2, 1), blk, 0, stream>>>(s16a, 16 * HW, b2w + 2 * 2304,
                                                   b2s + 32, b2t + 32, s16b, 16 * HW,
                                                   2 * HW);
  conv3x3<16, 16><<<dim3(g2, 1), blk, 0, stream>>>(s16b, 16 * HW, b2w + 3 * 2304,
                                                   b2s + 48, b2t + 48, s16a, 16 * HW,
                                                   2 * HW);
  conv3x3<16, 16><<<dim3(g2, 1), blk, 0, stream>>>(s16a, 16 * HW, b2w + 4 * 2304,
                                                   b2s + 64, b2t + 64, out + 4 * HW,
                                                   84 * HW, 2 * HW);

  // prepack AFTER block2 (s16a/s16b dead from here on)
  prepack<<<756, 256, 0, stream>>>(b3w0, b3w, Wt);

  // block3 via MFMA, per batch. pong_b = out ch20..83 of batch b reused as raw
  // bf16 storage (dead since block1-conv0; FINAL rewrites it as x3 fp32).
  dim3 mg(31 * 27, 1);  // 16x16-pixel tiles
  for (int b = 0; b < Bn; b++) {
    const float* x2b = out + (size_t)b * 84 * HW + (size_t)4 * HW;
    float* cb = out + (size_t)b * 84 * HW + (size_t)20 * HW;
    __bf16* pong = (__bf16*)cb;
    __bf16* n16 = (__bf16*)cb;  // n16 dead before pong first written (L1)
    cvt_nhwc16<<<(HW + 255) / 256, 256, 0, stream>>>(x2b, n16);
    mconv<16, false><<<mg, blk, 0, stream>>>(n16, Wt, b3s0, b3t0, ppA, nullptr);
    mconv<64, false><<<mg, blk, 0, stream>>>(ppA, Wt + 9216 + 0 * 36864, b3s + 0,
                                             b3t + 0, pong, nullptr);
    mconv<64, false><<<mg, blk, 0, stream>>>(pong, Wt + 9216 + 1 * 36864, b3s + 64,
                                             b3t + 64, ppA, nullptr);
    mconv<64, false><<<mg, blk, 0, stream>>>(ppA, Wt + 9216 + 2 * 36864, b3s + 128,
                                             b3t + 128, pong, nullptr);
    mconv<64, false><<<mg, blk, 0, stream>>>(pong, Wt + 9216 + 3 * 36864, b3s + 192,
                                             b3t + 192, ppA, nullptr);
    mconv<64, true><<<mg, blk, 0, stream>>>(ppA, Wt + 9216 + 4 * 36864, b3s + 256,
                                            b3t + 256, nullptr, cb);
  }
}

// Round 4
// 867.223 us; speedup vs baseline: 1.5672x; 1.0754x over previous
//
#include <hip/hip_runtime.h>
#include <math.h>

static constexpr int H = 496, W = 432, Bn = 2, Np = 16000;
static constexpr int HW = H * W;  // 214272

typedef __bf16 bf16x8 __attribute__((ext_vector_type(8)));
typedef float f32x16 __attribute__((ext_vector_type(16)));

// Gold-matching binning (R7-verified): multiply by f32-rounded reciprocal
// (RN_f32(1/0.16f) == 6.25f). DO NOT change to division.
__device__ inline void bin_xy(float px, float py, int& ix, int& iy) {
  ix = (int)floorf(px * 6.25f);
  iy = (int)floorf((py + 39.68f) * 6.25f);
  ix = min(max(ix, 0), W - 1);
  iy = min(max(iy, 0), H - 1);
}

// ---------------- Voxelization pass 1 ----------------
__global__ __launch_bounds__(256)
void count_kernel(const float* __restrict__ pts, int* __restrict__ cnt,
                  float* __restrict__ sums) {
  int p = blockIdx.x * blockDim.x + threadIdx.x;
  if (p >= Bn * Np) return;
  float px = pts[p * 4 + 0], py = pts[p * 4 + 1], pz = pts[p * 4 + 2];
  int b = p / Np;
  int ix, iy;
  bin_xy(px, py, ix, iy);
  int gid = b * HW + iy * W + ix;
  atomicAdd(&cnt[gid], 1);
  atomicAdd(&sums[3 * gid + 0], px);
  atomicAdd(&sums[3 * gid + 1], py);
  atomicAdd(&sums[3 * gid + 2], pz);
}

// ---------------- Voxelization pass 2: VFE + atomicMax scatter ----------------
__global__ __launch_bounds__(256)
void vfe_kernel(const float* __restrict__ pts, const int* __restrict__ cnt,
                const float* __restrict__ sums, const float* __restrict__ vw,
                const float* __restrict__ vs, const float* __restrict__ vt,
                float* __restrict__ out) {
  int tid = blockIdx.x * blockDim.x + threadIdx.x;
  if (tid >= Bn * Np * 64) return;
  int o = tid & 63;
  int p = tid >> 6;
  int b = p / Np;
  float px = pts[p * 4 + 0], py = pts[p * 4 + 1];
  float pz = pts[p * 4 + 2], pr = pts[p * 4 + 3];
  int ix, iy;
  bin_xy(px, py, ix, iy);
  int gid = b * HW + iy * W + ix;
  int n = cnt[gid];
  float denom = (float)max(n, 1);
  float mx = sums[3 * gid + 0] / denom;
  float my = sums[3 * gid + 1] / denom;
  float mz = sums[3 * gid + 2] / denom;
  float cx = (float)ix * 0.16f + 0.08f;
  float cy = (float)iy * 0.16f + (0.08f - 39.68f);
  float f[10] = {px, py, pz, pr, px - mx, py - my, pz - mz,
                 px - cx, py - cy, pz + 1.0f};
  const float* wr = vw + o * 10;
  float d = 0.f;
#pragma unroll
  for (int c = 0; c < 10; c++) d += f[c] * wr[c];
  float val = d * vs[o] + vt[o];
  val = fmaxf(val, 0.f);
  if (n < 32) val = fmaxf(val, fmaxf(vt[o], 0.f));
  unsigned int* dst = (unsigned int*)(out + (size_t)b * (84 * HW) +
                                      (size_t)(20 + o) * HW + (size_t)iy * W + ix);
  atomicMax(dst, __float_as_uint(val));
}

// ---------------- fp32 direct 3x3 conv (blocks 1 & 2 only) ----------------
template <int CI, int COT>
__global__ __launch_bounds__(256)
void conv3x3(const float* __restrict__ in, int in_bs, const float* __restrict__ w,
             const float* __restrict__ s, const float* __restrict__ t,
             float* __restrict__ out, int out_bs, int npix) {
  int pix = blockIdx.x * blockDim.x + threadIdx.x;
  if (pix >= npix) return;
  int b = pix / HW;
  int rem = pix - b * HW;
  int y = rem / W;
  int x = rem - y * W;
  int co0 = blockIdx.y * COT;
  const float* inb = in + (size_t)b * in_bs;

  int offs[9];
  bool okm[9];
#pragma unroll
  for (int ky = 0; ky < 3; ky++) {
    int yy = y + ky - 1;
    bool yok = (unsigned)yy < (unsigned)H;
#pragma unroll
    for (int kx = 0; kx < 3; kx++) {
      int xx = x + kx - 1;
      okm[ky * 3 + kx] = yok && ((unsigned)xx < (unsigned)W);
      offs[ky * 3 + kx] = yy * W + xx;
    }
  }
  float acc[COT];
#pragma unroll
  for (int i = 0; i < COT; i++) acc[i] = 0.f;
  for (int ci = 0; ci < CI; ci++) {
    const float* ip = inb + (size_t)ci * HW;
    float iv[9];
#pragma unroll
    for (int k = 0; k < 9; k++) iv[k] = okm[k] ? ip[offs[k]] : 0.f;
    const float* wp = w + ((size_t)co0 * CI + ci) * 9;
#pragma unroll
    for (int cg = 0; cg < COT; cg++) {
      const float* wc = wp + (size_t)cg * CI * 9;
#pragma unroll
      for (int k = 0; k < 9; k++) acc[cg] = fmaf(iv[k], wc[k], acc[cg]);
    }
  }
  float* ob = out + (size_t)b * out_bs + (size_t)rem;
#pragma unroll
  for (int cg = 0; cg < COT; cg++) {
    float v = acc[cg] * s[co0 + cg] + t[co0 + cg];
    ob[(size_t)(co0 + cg) * HW] = fmaxf(v, 0.f);
  }
}

// ---------------- weight prepack for block3 ----------------
// Fragment-ordered layout so a wave's B-frag load is ONE CONTIGUOUS 1KB block:
//   per (tap, kc[16-wide K step], ntile) a 512-elem block laid out as
//   [co32][khalf][8 elems]; lane l reads 16B at (l&31)*32B + (l>>5)*16B
//   -> 64 lanes cover exactly bytes [0,1024).
__global__ __launch_bounds__(256)
void prepack(const float* __restrict__ w0, const float* __restrict__ ws,
             __bf16* __restrict__ wt) {
  int idx = blockIdx.x * 256 + threadIdx.x;
  const int E0 = 64 * 144, EN = 64 * 576;
  if (idx < E0) {
    // layer0 CI=16: block = tp*2+nt (KC=1)
    int blk = idx >> 9, rem = idx & 511;
    int tp = blk >> 1, nt = blk & 1;
    int co = nt * 32 + (rem >> 4);
    int ci = rem & 15;  // = khalf*8 + e
    int ky = tp / 3, kx = tp - ky * 3;
    wt[idx] = (__bf16)w0[((co * 16 + ci) * 3 + ky) * 3 + kx];
  } else {
    int j = idx - E0;
    if (j >= 5 * EN) return;
    int n = j / EN, rr = j - n * EN;
    // CI=64: block = (tp*4+kc)*2+nt
    int blk = rr >> 9, rem = rr & 511;
    int tpkc = blk >> 1, nt = blk & 1;
    int tp = tpkc >> 2, kc = tpkc & 3;
    int co = nt * 32 + (rem >> 4);
    int ci = kc * 16 + (rem & 15);
    int ky = tp / 3, kx = tp - ky * 3;
    wt[idx] = (__bf16)ws[n * 36864 + ((co * 64 + ci) * 3 + ky) * 3 + kx];
  }
}

// ---------------- x2 (NCHW fp32) -> NHWC bf16, BOTH batches ----------------
// x2 must point at CHANNEL 4 of batch 0 (x2 = out ch4..19); per-batch stride
// 84*HW floats. (R3 bug: passed `out` = ch0 -> read x1 as input. FIXED.)
__global__ __launch_bounds__(256)
void cvt_nhwc16(const float* __restrict__ x2, __bf16* __restrict__ n16) {
  int q = blockIdx.x * 256 + threadIdx.x;
  if (q >= Bn * HW) return;
  int b = q / HW;
  int p = q - b * HW;
  const float* x2b = x2 + (size_t)b * 84 * HW;
  __bf16* nb = n16 + (size_t)b * 84 * HW * 2;
  __bf16 v[16];
#pragma unroll
  for (int ci = 0; ci < 16; ci++) v[ci] = (__bf16)x2b[(size_t)ci * HW + p];
  *(bf16x8*)(nb + (size_t)p * 16) = *(bf16x8*)v;
  *(bf16x8*)(nb + (size_t)p * 16 + 8) = *(bf16x8*)(v + 8);
}

// ---------------- MFMA implicit-GEMM 3x3 conv, NHWC bf16 in, BOTH batches ------
// wg = 256 thr (4 waves), tile 16x16 pixels x 64 co. Halo (18x18 x CI) staged
// once in LDS. Wave wv owns 64 px as 2 m-tiles x 2 n-tiles (4 f32x16 accs).
// Tap-level double-buffered fragment pipeline (tp+1 loads issued before tp's
// 16 MFMAs). grid = (837, Bn): both batches in ONE dispatch -> 6-deep layer
// chain instead of 12, ~2x blocks per dispatch (better slot utilization),
// half the launch gaps. Per-batch arithmetic identical -> bitwise-same output.
// Strides are in ELEMENTS of the respective pointee type.
// FINAL: BN+ReLU then LDS-transpose (two 128-px chunks) -> coalesced NCHW fp32.
template <int CI, bool FINAL>
__global__ __launch_bounds__(256, 2)
void mconv(const __bf16* __restrict__ in, size_t in_bstride,
           const __bf16* __restrict__ wt, const float* __restrict__ s,
           const float* __restrict__ t, __bf16* __restrict__ outb,
           size_t outb_bstride, float* __restrict__ outf, size_t outf_bstride) {
  constexpr int KC = CI / 16;
  constexpr int PADW = (CI == 64) ? 72 : 24;  // bf16 per-pixel stride; 16B-aligned
  constexpr int HALO_B = 324 * PADW * 2;      // 18x18 pixels
  constexpr int TRAN_B = FINAL ? 128 * 66 * 4 : 0;
  constexpr int SMEM_B = HALO_B > TRAN_B ? HALO_B : TRAN_B;  // 46656 for CI=64
  __shared__ __align__(16) char smem[SMEM_B];
  __bf16* hl = (__bf16*)smem;

  const int tid = threadIdx.x;
  const int bz = blockIdx.y;
  const int ty = blockIdx.x / 27, tx = blockIdx.x - ty * 27;
  const int y0 = ty * 16, x0 = tx * 16;
  in += (size_t)bz * in_bstride;

  // stage halo: 18x18 pixels x CI channels (zeros outside image)
  constexpr int NCH = CI / 8;
  constexpr int TOT = 324 * NCH;
  for (int q = tid; q < TOT; q += 256) {
    int hp = q / NCH, c8 = q - hp * NCH;
    int hy = hp / 18, hx = hp - hy * 18;
    int gy = y0 - 1 + hy, gx = x0 - 1 + hx;
    int4 v = {0, 0, 0, 0};
    if ((unsigned)gy < (unsigned)H && (unsigned)gx < (unsigned)W)
      v = *(const int4*)(in + (size_t)(gy * W + gx) * CI + c8 * 8);
    *(int4*)(hl + hp * PADW + c8 * 8) = v;
  }
  __syncthreads();

  const int lane = tid & 63;
  const int wv = tid >> 6;
  const int col = lane & 31, half = lane >> 5;
  const int ly0 = 4 * wv + (col >> 4);  // A: m = col -> pixel row of m-tile 0
  const int lx = col & 15;

  f32x16 z = {0.f, 0.f, 0.f, 0.f, 0.f, 0.f, 0.f, 0.f,
              0.f, 0.f, 0.f, 0.f, 0.f, 0.f, 0.f, 0.f};
  f32x16 a00 = z, a01 = z, a10 = z, a11 = z;  // [mtile][ntile]

  const int laneoff = col * 16 + half * 8;
  const __bf16* wbase = wt + laneoff;

  // double-buffered fragment sets (all indices compile-time after unroll)
  bf16x8 Af0[2][KC], Af1[2][KC], Bf0[2][KC], Bf1[2][KC];

  auto LOADTAP = [&](int tp, int buf) {
    const __bf16* a0r = hl + ((ly0 + tp / 3) * 18 + lx + tp % 3) * PADW + half * 8;
    const __bf16* a1r = a0r + 2 * 18 * PADW;  // m-tile 1: +2 pixel rows
    const __bf16* bb = wbase + ((tp * KC) << 10);
#pragma unroll
    for (int kc = 0; kc < KC; ++kc) {
      Af0[buf][kc] = *(const bf16x8*)(a0r + kc * 16);
      Af1[buf][kc] = *(const bf16x8*)(a1r + kc * 16);
      Bf0[buf][kc] = *(const bf16x8*)(bb + (kc << 10));
      Bf1[buf][kc] = *(const bf16x8*)(bb + (kc << 10) + 512);
    }
  };

  LOADTAP(0, 0);
#pragma unroll
  for (int tp = 0; tp < 9; ++tp) {
    const int cur = tp & 1;
    if (tp < 8) LOADTAP(tp + 1, cur ^ 1);  // prefetch next tap under MFMAs
#pragma unroll
    for (int kc = 0; kc < KC; ++kc) {
      a00 = __builtin_amdgcn_mfma_f32_32x32x16_bf16(Af0[cur][kc], Bf0[cur][kc],
                                                    a00, 0, 0, 0);
      a01 = __builtin_amdgcn_mfma_f32_32x32x16_bf16(Af0[cur][kc], Bf1[cur][kc],
                                                    a01, 0, 0, 0);
      a10 = __builtin_amdgcn_mfma_f32_32x32x16_bf16(Af1[cur][kc], Bf0[cur][kc],
                                                    a10, 0, 0, 0);
      a11 = __builtin_amdgcn_mfma_f32_32x32x16_bf16(Af1[cur][kc], Bf1[cur][kc],
                                                    a11, 0, 0, 0);
    }
  }

  float s0 = s[col], t0v = t[col], s1 = s[col + 32], t1v = t[col + 32];
  if constexpr (!FINAL) {
    __bf16* ob = outb + (size_t)bz * outb_bstride;
#pragma unroll
    for (int r = 0; r < 16; ++r) {
      int row = (r & 3) + 8 * (r >> 2) + 4 * half;  // verified C/D map (m74/m101)
      int py = y0 + 4 * wv + (row >> 4);
      int px = x0 + (row & 15);
      size_t gp0 = (size_t)py * W + px;
      size_t gp1 = gp0 + (size_t)2 * W;  // m-tile 1
      ob[gp0 * 64 + col] = (__bf16)fmaxf(a00[r] * s0 + t0v, 0.f);
      ob[gp0 * 64 + col + 32] = (__bf16)fmaxf(a01[r] * s1 + t1v, 0.f);
      ob[gp1 * 64 + col] = (__bf16)fmaxf(a10[r] * s0 + t0v, 0.f);
      ob[gp1 * 64 + col + 32] = (__bf16)fmaxf(a11[r] * s1 + t1v, 0.f);
    }
  } else {
    float* of = outf + (size_t)bz * outf_bstride;
    float* tl = (float*)smem;
    // two 128-pixel chunks (waves {0,1} then {2,3}) so tl fits under halo size
    for (int h = 0; h < 2; ++h) {
      __syncthreads();  // h=0: halo reads done; h=1: chunk-0 stores done
      if ((wv >> 1) == h) {
        int wl = wv & 1;
#pragma unroll
        for (int r = 0; r < 16; ++r) {
          int row = (r & 3) + 8 * (r >> 2) + 4 * half;
          int lp0 = (4 * wl + (row >> 4)) * 16 + (row & 15);
          int lp1 = lp0 + 32;  // +2 pixel rows
          tl[lp0 * 66 + col] = fmaxf(a00[r] * s0 + t0v, 0.f);
          tl[lp0 * 66 + col + 32] = fmaxf(a01[r] * s1 + t1v, 0.f);
          tl[lp1 * 66 + col] = fmaxf(a10[r] * s0 + t0v, 0.f);
          tl[lp1 * 66 + col + 32] = fmaxf(a11[r] * s1 + t1v, 0.f);
        }
      }
      __syncthreads();
      for (int e = tid; e < 128 * 64; e += 256) {
        int co = e >> 7, mtl = e & 127;
        of[(size_t)co * HW + (size_t)(y0 + h * 8 + (mtl >> 4)) * W +
           (x0 + (mtl & 15))] = tl[mtl * 66 + co];
      }
    }
  }
}

extern "C" void kernel_launch(void* const* d_in, const int* in_sizes, int n_in,
                              void* d_out, int out_size, void* d_ws, size_t ws_size,
                              hipStream_t stream) {
  const float* pts  = (const float*)d_in[0];
  const float* vw   = (const float*)d_in[1];
  const float* vs   = (const float*)d_in[2];
  const float* vt   = (const float*)d_in[3];
  const float* b1w0 = (const float*)d_in[4];
  const float* b1s0 = (const float*)d_in[5];
  const float* b1t0 = (const float*)d_in[6];
  const float* b1w  = (const float*)d_in[7];
  const float* b1s  = (const float*)d_in[8];
  const float* b1t  = (const float*)d_in[9];
  const float* b2w0 = (const float*)d_in[10];
  const float* b2s0 = (const float*)d_in[11];
  const float* b2t0 = (const float*)d_in[12];
  const float* b2w  = (const float*)d_in[13];
  const float* b2s  = (const float*)d_in[14];
  const float* b2t  = (const float*)d_in[15];
  const float* b3w0 = (const float*)d_in[16];
  const float* b3s0 = (const float*)d_in[17];
  const float* b3t0 = (const float*)d_in[18];
  const float* b3w  = (const float*)d_in[19];
  const float* b3s  = (const float*)d_in[20];
  const float* b3t  = (const float*)d_in[21];
  float* out = (float*)d_out;

  // ws layout:
  //  phase vox:     cnt [0,2HW) ints + sums [2HW,8HW) floats
  //  phase blk1/2:  s16a [0,32HW) + s16b [32HW,64HW) floats
  //  phase blk3:    ppA(b) bf16 at b*64HW elems, spans [0, 64HW*4 bytes)
  //  Wt bf16 at byte 64*HW*4 (387 KB) - disjoint from all of the above,
  //  written by prepack up front (depends only on b3 weights).
  float* wsf = (float*)d_ws;
  int* cnt = (int*)wsf;
  float* sums = wsf + (size_t)2 * HW;
  float* s16a = wsf;
  float* s16b = wsf + (size_t)32 * HW;
  __bf16* ppA = (__bf16*)d_ws;                       // + b*64*HW elements
  __bf16* Wt = (__bf16*)((char*)d_ws + (size_t)64 * HW * 4);

  // prepack first: no deps, off the critical path
  prepack<<<756, 256, 0, stream>>>(b3w0, b3w, Wt);

  hipMemsetAsync(out + (size_t)20 * HW, 0, (size_t)64 * HW * sizeof(float), stream);
  hipMemsetAsync(out + (size_t)(84 + 20) * HW, 0, (size_t)64 * HW * sizeof(float),
                 stream);
  hipMemsetAsync(cnt, 0, (size_t)8 * HW * sizeof(float), stream);

  count_kernel<<<(Bn * Np + 255) / 256, 256, 0, stream>>>(pts, cnt, sums);
  vfe_kernel<<<(Bn * Np * 64 + 255) / 256, 256, 0, stream>>>(pts, cnt, sums, vw, vs,
                                                             vt, out);

  const int g2 = (2 * HW + 255) / 256;
  dim3 blk(256);
  float* canvas = out + (size_t)20 * HW;

  // block1: 64->4, 3x(4->4); x1 -> out ch0..3
  conv3x3<64, 4><<<dim3(g2, 1), blk, 0, stream>>>(canvas, 84 * HW, b1w0, b1s0, b1t0,
                                                  s16a, 4 * HW, 2 * HW);
  conv3x3<4, 4><<<dim3(g2, 1), blk, 0, stream>>>(s16a, 4 * HW, b1w + 0 * 144,
                                                 b1s + 0, b1t + 0, s16b, 4 * HW,
                                                 2 * HW);
  conv3x3<4, 4><<<dim3(g2, 1), blk, 0, stream>>>(s16b, 4 * HW, b1w + 1 * 144,
                                                 b1s + 4, b1t + 4, s16a, 4 * HW,
                                                 2 * HW);
  conv3x3<4, 4><<<dim3(g2, 1), blk, 0, stream>>>(s16a, 4 * HW, b1w + 2 * 144,
                                                 b1s + 8, b1t + 8, out, 84 * HW,
                                                 2 * HW);

  // block2: 4->16, 5x(16->16); x2 -> out ch4..19
  conv3x3<4, 16><<<dim3(g2, 1), blk, 0, stream>>>(out, 84 * HW, b2w0, b2s0, b2t0,
                                                  s16a, 16 * HW, 2 * HW);
  conv3x3<16, 16><<<dim3(g2, 1), blk, 0, stream>>>(s16a, 16 * HW, b2w + 0 * 2304,
                                                   b2s + 0, b2t + 0, s16b, 16 * HW,
                                                   2 * HW);
  conv3x3<16, 16><<<dim3(g2, 1), blk, 0, stream>>>(s16b, 16 * HW, b2w + 1 * 2304,
                                                   b2s + 16, b2t + 16, s16a, 16 * HW,
                                                   2 * HW);
  conv3x3<16, 16><<<dim3(g2, 1), blk, 0, stream>>>(s16a, 16 * HW, b2w + 2 * 2304,
                                                   b2s + 32, b2t + 32, s16b, 16 * HW,
                                                   2 * HW);
  conv3x3<16, 16><<<dim3(g2, 1), blk, 0, stream>>>(s16b, 16 * HW, b2w + 3 * 2304,
                                                   b2s + 48, b2t + 48, s16a, 16 * HW,
                                                   2 * HW);
  conv3x3<16, 16><<<dim3(g2, 1), blk, 0, stream>>>(s16a, 16 * HW, b2w + 4 * 2304,
                                                   b2s + 64, b2t + 64, out + 4 * HW,
                                                   84 * HW, 2 * HW);

  // block3 via MFMA, BOTH batches per dispatch (grid.y = Bn).
  // n16/pong live in out ch20..83 of each batch (dead canvas; FINAL rewrites
  // as x3 fp32). ppA(b) at ws + b*64HW bf16. Layer l for both batches finishes
  // before layer l+1 starts (separate dispatches) -> same per-batch ordering.
  __bf16* n16 = (__bf16*)canvas;            // per-batch stride 84*HW*2 bf16 elems
  const size_t canv_s = (size_t)84 * HW * 2;
  const size_t ppa_s = (size_t)64 * HW;
  // input = x2 = out ch4..19  (R3 bug was passing `out` = ch0)
  cvt_nhwc16<<<(Bn * HW + 255) / 256, 256, 0, stream>>>(out + (size_t)4 * HW, n16);
  dim3 mg(31 * 27, Bn);  // 16x16-pixel tiles x batches
  mconv<16, false><<<mg, blk, 0, stream>>>(n16, canv_s, Wt, b3s0, b3t0, ppA, ppa_s,
                                           nullptr, 0);
  mconv<64, false><<<mg, blk, 0, stream>>>(ppA, ppa_s, Wt + 9216 + 0 * 36864,
                                           b3s + 0, b3t + 0, n16, canv_s, nullptr,
                                           0);
  mconv<64, false><<<mg, blk, 0, stream>>>(n16, canv_s, Wt + 9216 + 1 * 36864,
                                           b3s + 64, b3t + 64, ppA, ppa_s, nullptr,
                                           0);
  mconv<64, false><<<mg, blk, 0, stream>>>(ppA, ppa_s, Wt + 9216 + 2 * 36864,
                                           b3s + 128, b3t + 128, n16, canv_s,
                                           nullptr, 0);
  mconv<64, false><<<mg, blk, 0, stream>>>(n16, canv_s, Wt + 9216 + 3 * 36864,
                                           b3s + 192, b3t + 192, ppA, ppa_s,
                                           nullptr, 0);
  mconv<64, true><<<mg, blk, 0, stream>>>(ppA, ppa_s, Wt + 9216 + 4 * 36864,
                                          b3s + 256, b3t + 256, nullptr, 0, canvas,
                                          (size_t)84 * HW);
}

// Round 5
// 866.101 us; speedup vs baseline: 1.5692x; 1.0013x over previous
//
#include <hip/hip_runtime.h>
#include <math.h>

static constexpr int H = 496, W = 432, Bn = 2, Np = 16000;
static constexpr int HW = H * W;  // 214272

typedef __bf16 bf16x8 __attribute__((ext_vector_type(8)));
typedef float f32x16 __attribute__((ext_vector_type(16)));

// Gold-matching binning (R7-verified): multiply by f32-rounded reciprocal
// (RN_f32(1/0.16f) == 6.25f). DO NOT change to division.
__device__ inline void bin_xy(float px, float py, int& ix, int& iy) {
  ix = (int)floorf(px * 6.25f);
  iy = (int)floorf((py + 39.68f) * 6.25f);
  ix = min(max(ix, 0), W - 1);
  iy = min(max(iy, 0), H - 1);
}

// ---------------- Voxelization pass 1 ----------------
__global__ __launch_bounds__(256)
void count_kernel(const float* __restrict__ pts, int* __restrict__ cnt,
                  float* __restrict__ sums) {
  int p = blockIdx.x * blockDim.x + threadIdx.x;
  if (p >= Bn * Np) return;
  float px = pts[p * 4 + 0], py = pts[p * 4 + 1], pz = pts[p * 4 + 2];
  int b = p / Np;
  int ix, iy;
  bin_xy(px, py, ix, iy);
  int gid = b * HW + iy * W + ix;
  atomicAdd(&cnt[gid], 1);
  atomicAdd(&sums[3 * gid + 0], px);
  atomicAdd(&sums[3 * gid + 1], py);
  atomicAdd(&sums[3 * gid + 2], pz);
}

// ---------------- Voxelization pass 2: VFE + atomicMax scatter ----------------
__global__ __launch_bounds__(256)
void vfe_kernel(const float* __restrict__ pts, const int* __restrict__ cnt,
                const float* __restrict__ sums, const float* __restrict__ vw,
                const float* __restrict__ vs, const float* __restrict__ vt,
                float* __restrict__ out) {
  int tid = blockIdx.x * blockDim.x + threadIdx.x;
  if (tid >= Bn * Np * 64) return;
  int o = tid & 63;
  int p = tid >> 6;
  int b = p / Np;
  float px = pts[p * 4 + 0], py = pts[p * 4 + 1];
  float pz = pts[p * 4 + 2], pr = pts[p * 4 + 3];
  int ix, iy;
  bin_xy(px, py, ix, iy);
  int gid = b * HW + iy * W + ix;
  int n = cnt[gid];
  float denom = (float)max(n, 1);
  float mx = sums[3 * gid + 0] / denom;
  float my = sums[3 * gid + 1] / denom;
  float mz = sums[3 * gid + 2] / denom;
  float cx = (float)ix * 0.16f + 0.08f;
  float cy = (float)iy * 0.16f + (0.08f - 39.68f);
  float f[10] = {px, py, pz, pr, px - mx, py - my, pz - mz,
                 px - cx, py - cy, pz + 1.0f};
  const float* wr = vw + o * 10;
  float d = 0.f;
#pragma unroll
  for (int c = 0; c < 10; c++) d += f[c] * wr[c];
  float val = d * vs[o] + vt[o];
  val = fmaxf(val, 0.f);
  if (n < 32) val = fmaxf(val, fmaxf(vt[o], 0.f));
  unsigned int* dst = (unsigned int*)(out + (size_t)b * (84 * HW) +
                                      (size_t)(20 + o) * HW + (size_t)iy * W + ix);
  atomicMax(dst, __float_as_uint(val));
}

// ---------------- fp32 direct 3x3 conv (blocks 1 & 2 only) ----------------
template <int CI, int COT>
__global__ __launch_bounds__(256)
void conv3x3(const float* __restrict__ in, int in_bs, const float* __restrict__ w,
             const float* __restrict__ s, const float* __restrict__ t,
             float* __restrict__ out, int out_bs, int npix) {
  int pix = blockIdx.x * blockDim.x + threadIdx.x;
  if (pix >= npix) return;
  int b = pix / HW;
  int rem = pix - b * HW;
  int y = rem / W;
  int x = rem - y * W;
  int co0 = blockIdx.y * COT;
  const float* inb = in + (size_t)b * in_bs;

  int offs[9];
  bool okm[9];
#pragma unroll
  for (int ky = 0; ky < 3; ky++) {
    int yy = y + ky - 1;
    bool yok = (unsigned)yy < (unsigned)H;
#pragma unroll
    for (int kx = 0; kx < 3; kx++) {
      int xx = x + kx - 1;
      okm[ky * 3 + kx] = yok && ((unsigned)xx < (unsigned)W);
      offs[ky * 3 + kx] = yy * W + xx;
    }
  }
  float acc[COT];
#pragma unroll
  for (int i = 0; i < COT; i++) acc[i] = 0.f;
  for (int ci = 0; ci < CI; ci++) {
    const float* ip = inb + (size_t)ci * HW;
    float iv[9];
#pragma unroll
    for (int k = 0; k < 9; k++) iv[k] = okm[k] ? ip[offs[k]] : 0.f;
    const float* wp = w + ((size_t)co0 * CI + ci) * 9;
#pragma unroll
    for (int cg = 0; cg < COT; cg++) {
      const float* wc = wp + (size_t)cg * CI * 9;
#pragma unroll
      for (int k = 0; k < 9; k++) acc[cg] = fmaf(iv[k], wc[k], acc[cg]);
    }
  }
  float* ob = out + (size_t)b * out_bs + (size_t)rem;
#pragma unroll
  for (int cg = 0; cg < COT; cg++) {
    float v = acc[cg] * s[co0 + cg] + t[co0 + cg];
    ob[(size_t)(co0 + cg) * HW] = fmaxf(v, 0.f);
  }
}

// ---------------- weight prepack for block3 ----------------
// Fragment-ordered layout so a wave's B-frag load is ONE CONTIGUOUS 1KB block:
//   per (tap, kc[16-wide K step], ntile) a 512-elem block laid out as
//   [co32][khalf][8 elems]; lane l reads 16B at (l&31)*32B + (l>>5)*16B
//   -> 64 lanes cover exactly bytes [0,1024).
__global__ __launch_bounds__(256)
void prepack(const float* __restrict__ w0, const float* __restrict__ ws,
             __bf16* __restrict__ wt) {
  int idx = blockIdx.x * 256 + threadIdx.x;
  const int E0 = 64 * 144, EN = 64 * 576;
  if (idx < E0) {
    // layer0 CI=16: block = tp*2+nt (KC=1)
    int blk = idx >> 9, rem = idx & 511;
    int tp = blk >> 1, nt = blk & 1;
    int co = nt * 32 + (rem >> 4);
    int ci = rem & 15;  // = khalf*8 + e
    int ky = tp / 3, kx = tp - ky * 3;
    wt[idx] = (__bf16)w0[((co * 16 + ci) * 3 + ky) * 3 + kx];
  } else {
    int j = idx - E0;
    if (j >= 5 * EN) return;
    int n = j / EN, rr = j - n * EN;
    // CI=64: block = (tp*4+kc)*2+nt
    int blk = rr >> 9, rem = rr & 511;
    int tpkc = blk >> 1, nt = blk & 1;
    int tp = tpkc >> 2, kc = tpkc & 3;
    int co = nt * 32 + (rem >> 4);
    int ci = kc * 16 + (rem & 15);
    int ky = tp / 3, kx = tp - ky * 3;
    wt[idx] = (__bf16)ws[n * 36864 + ((co * 64 + ci) * 3 + ky) * 3 + kx];
  }
}

// ---------------- x2 (NCHW fp32) -> NHWC bf16, BOTH batches ----------------
// x2 must point at CHANNEL 4 of batch 0 (x2 = out ch4..19); per-batch stride
// 84*HW floats.
__global__ __launch_bounds__(256)
void cvt_nhwc16(const float* __restrict__ x2, __bf16* __restrict__ n16) {
  int q = blockIdx.x * 256 + threadIdx.x;
  if (q >= Bn * HW) return;
  int b = q / HW;
  int p = q - b * HW;
  const float* x2b = x2 + (size_t)b * 84 * HW;
  __bf16* nb = n16 + (size_t)b * 84 * HW * 2;
  __bf16 v[16];
#pragma unroll
  for (int ci = 0; ci < 16; ci++) v[ci] = (__bf16)x2b[(size_t)ci * HW + p];
  *(bf16x8*)(nb + (size_t)p * 16) = *(bf16x8*)v;
  *(bf16x8*)(nb + (size_t)p * 16 + 8) = *(bf16x8*)(v + 8);
}

// ---------------- MFMA implicit-GEMM 3x3 conv, NHWC bf16 in, BOTH batches ------
// wg = 256 thr (4 waves), tile 16x16 pixels x 64 co. Halo (18x18 x CI) staged
// once in LDS. Wave wv owns 64 px as 2 m-tiles x 2 n-tiles (4 f32x16 accs).
// R5: dropped the explicit tap double-buffer (R2 proved it neutral — compiler
// already schedules the fully-unrolled loop) and declared min 3 waves/SIMD.
// The frag arrays alone cost 128 VGPR; removing them + the (256,3) bound caps
// the allocator at ~170 VGPR -> 3 blocks/CU (LDS 46.7KB <= 53.3KB fits) for
// 1.5x the latency-hiding. Accumulation order unchanged -> bitwise-identical.
// FINAL: BN+ReLU then LDS-transpose (two 128-px chunks) -> coalesced NCHW fp32.
template <int CI, bool FINAL>
__global__ __launch_bounds__(256, 3)
void mconv(const __bf16* __restrict__ in, size_t in_bstride,
           const __bf16* __restrict__ wt, const float* __restrict__ s,
           const float* __restrict__ t, __bf16* __restrict__ outb,
           size_t outb_bstride, float* __restrict__ outf, size_t outf_bstride) {
  constexpr int KC = CI / 16;
  constexpr int PADW = (CI == 64) ? 72 : 24;  // bf16 per-pixel stride; 16B-aligned
  constexpr int HALO_B = 324 * PADW * 2;      // 18x18 pixels
  constexpr int TRAN_B = FINAL ? 128 * 66 * 4 : 0;
  constexpr int SMEM_B = HALO_B > TRAN_B ? HALO_B : TRAN_B;  // 46656 for CI=64
  __shared__ __align__(16) char smem[SMEM_B];
  __bf16* hl = (__bf16*)smem;

  const int tid = threadIdx.x;
  const int bz = blockIdx.y;
  const int ty = blockIdx.x / 27, tx = blockIdx.x - ty * 27;
  const int y0 = ty * 16, x0 = tx * 16;
  in += (size_t)bz * in_bstride;

  // stage halo: 18x18 pixels x CI channels (zeros outside image)
  constexpr int NCH = CI / 8;
  constexpr int TOT = 324 * NCH;
  for (int q = tid; q < TOT; q += 256) {
    int hp = q / NCH, c8 = q - hp * NCH;
    int hy = hp / 18, hx = hp - hy * 18;
    int gy = y0 - 1 + hy, gx = x0 - 1 + hx;
    int4 v = {0, 0, 0, 0};
    if ((unsigned)gy < (unsigned)H && (unsigned)gx < (unsigned)W)
      v = *(const int4*)(in + (size_t)(gy * W + gx) * CI + c8 * 8);
    *(int4*)(hl + hp * PADW + c8 * 8) = v;
  }
  __syncthreads();

  const int lane = tid & 63;
  const int wv = tid >> 6;
  const int col = lane & 31, half = lane >> 5;
  const int ly0 = 4 * wv + (col >> 4);  // A: m = col -> pixel row of m-tile 0
  const int lx = col & 15;

  f32x16 z = {0.f, 0.f, 0.f, 0.f, 0.f, 0.f, 0.f, 0.f,
              0.f, 0.f, 0.f, 0.f, 0.f, 0.f, 0.f, 0.f};
  f32x16 a00 = z, a01 = z, a10 = z, a11 = z;  // [mtile][ntile]

  const int laneoff = col * 16 + half * 8;
  const __bf16* wbase = wt + laneoff;

#pragma unroll
  for (int tp = 0; tp < 9; ++tp) {
    const __bf16* a0r = hl + ((ly0 + tp / 3) * 18 + lx + tp % 3) * PADW + half * 8;
    const __bf16* a1r = a0r + 2 * 18 * PADW;  // m-tile 1: +2 pixel rows
    const __bf16* bb = wbase + ((tp * KC) << 10);
#pragma unroll
    for (int kc = 0; kc < KC; ++kc) {
      bf16x8 af0 = *(const bf16x8*)(a0r + kc * 16);
      bf16x8 af1 = *(const bf16x8*)(a1r + kc * 16);
      bf16x8 b0 = *(const bf16x8*)(bb + (kc << 10));
      bf16x8 b1 = *(const bf16x8*)(bb + (kc << 10) + 512);
      a00 = __builtin_amdgcn_mfma_f32_32x32x16_bf16(af0, b0, a00, 0, 0, 0);
      a01 = __builtin_amdgcn_mfma_f32_32x32x16_bf16(af0, b1, a01, 0, 0, 0);
      a10 = __builtin_amdgcn_mfma_f32_32x32x16_bf16(af1, b0, a10, 0, 0, 0);
      a11 = __builtin_amdgcn_mfma_f32_32x32x16_bf16(af1, b1, a11, 0, 0, 0);
    }
  }

  float s0 = s[col], t0v = t[col], s1 = s[col + 32], t1v = t[col + 32];
  if constexpr (!FINAL) {
    __bf16* ob = outb + (size_t)bz * outb_bstride;
#pragma unroll
    for (int r = 0; r < 16; ++r) {
      int row = (r & 3) + 8 * (r >> 2) + 4 * half;  // verified C/D map (m74/m101)
      int py = y0 + 4 * wv + (row >> 4);
      int px = x0 + (row & 15);
      size_t gp0 = (size_t)py * W + px;
      size_t gp1 = gp0 + (size_t)2 * W;  // m-tile 1
      ob[gp0 * 64 + col] = (__bf16)fmaxf(a00[r] * s0 + t0v, 0.f);
      ob[gp0 * 64 + col + 32] = (__bf16)fmaxf(a01[r] * s1 + t1v, 0.f);
      ob[gp1 * 64 + col] = (__bf16)fmaxf(a10[r] * s0 + t0v, 0.f);
      ob[gp1 * 64 + col + 32] = (__bf16)fmaxf(a11[r] * s1 + t1v, 0.f);
    }
  } else {
    float* of = outf + (size_t)bz * outf_bstride;
    float* tl = (float*)smem;
    // two 128-pixel chunks (waves {0,1} then {2,3}) so tl fits under halo size
    for (int h = 0; h < 2; ++h) {
      __syncthreads();  // h=0: halo reads done; h=1: chunk-0 stores done
      if ((wv >> 1) == h) {
        int wl = wv & 1;
#pragma unroll
        for (int r = 0; r < 16; ++r) {
          int row = (r & 3) + 8 * (r >> 2) + 4 * half;
          int lp0 = (4 * wl + (row >> 4)) * 16 + (row & 15);
          int lp1 = lp0 + 32;  // +2 pixel rows
          tl[lp0 * 66 + col] = fmaxf(a00[r] * s0 + t0v, 0.f);
          tl[lp0 * 66 + col + 32] = fmaxf(a01[r] * s1 + t1v, 0.f);
          tl[lp1 * 66 + col] = fmaxf(a10[r] * s0 + t0v, 0.f);
          tl[lp1 * 66 + col + 32] = fmaxf(a11[r] * s1 + t1v, 0.f);
        }
      }
      __syncthreads();
      for (int e = tid; e < 128 * 64; e += 256) {
        int co = e >> 7, mtl = e & 127;
        of[(size_t)co * HW + (size_t)(y0 + h * 8 + (mtl >> 4)) * W +
           (x0 + (mtl & 15))] = tl[mtl * 66 + co];
      }
    }
  }
}

extern "C" void kernel_launch(void* const* d_in, const int* in_sizes, int n_in,
                              void* d_out, int out_size, void* d_ws, size_t ws_size,
                              hipStream_t stream) {
  const float* pts  = (const float*)d_in[0];
  const float* vw   = (const float*)d_in[1];
  const float* vs   = (const float*)d_in[2];
  const float* vt   = (const float*)d_in[3];
  const float* b1w0 = (const float*)d_in[4];
  const float* b1s0 = (const float*)d_in[5];
  const float* b1t0 = (const float*)d_in[6];
  const float* b1w  = (const float*)d_in[7];
  const float* b1s  = (const float*)d_in[8];
  const float* b1t  = (const float*)d_in[9];
  const float* b2w0 = (const float*)d_in[10];
  const float* b2s0 = (const float*)d_in[11];
  const float* b2t0 = (const float*)d_in[12];
  const float* b2w  = (const float*)d_in[13];
  const float* b2s  = (const float*)d_in[14];
  const float* b2t  = (const float*)d_in[15];
  const float* b3w0 = (const float*)d_in[16];
  const float* b3s0 = (const float*)d_in[17];
  const float* b3t0 = (const float*)d_in[18];
  const float* b3w  = (const float*)d_in[19];
  const float* b3s  = (const float*)d_in[20];
  const float* b3t  = (const float*)d_in[21];
  float* out = (float*)d_out;

  // ws layout:
  //  phase vox:     cnt [0,2HW) ints + sums [2HW,8HW) floats
  //  phase blk1/2:  s16a [0,32HW) + s16b [32HW,64HW) floats
  //  phase blk3:    ppA(b) bf16 at b*64HW elems, spans [0, 64HW*4 bytes)
  //  Wt bf16 at byte 64*HW*4 (387 KB) - disjoint from all of the above,
  //  written by prepack up front (depends only on b3 weights).
  float* wsf = (float*)d_ws;
  int* cnt = (int*)wsf;
  float* sums = wsf + (size_t)2 * HW;
  float* s16a = wsf;
  float* s16b = wsf + (size_t)32 * HW;
  __bf16* ppA = (__bf16*)d_ws;                       // + b*64*HW elements
  __bf16* Wt = (__bf16*)((char*)d_ws + (size_t)64 * HW * 4);

  // prepack first: no deps, off the critical path
  prepack<<<756, 256, 0, stream>>>(b3w0, b3w, Wt);

  hipMemsetAsync(out + (size_t)20 * HW, 0, (size_t)64 * HW * sizeof(float), stream);
  hipMemsetAsync(out + (size_t)(84 + 20) * HW, 0, (size_t)64 * HW * sizeof(float),
                 stream);
  hipMemsetAsync(cnt, 0, (size_t)8 * HW * sizeof(float), stream);

  count_kernel<<<(Bn * Np + 255) / 256, 256, 0, stream>>>(pts, cnt, sums);
  vfe_kernel<<<(Bn * Np * 64 + 255) / 256, 256, 0, stream>>>(pts, cnt, sums, vw, vs,
                                                             vt, out);

  const int g2 = (2 * HW + 255) / 256;
  dim3 blk(256);
  float* canvas = out + (size_t)20 * HW;

  // block1: 64->4, 3x(4->4); x1 -> out ch0..3
  conv3x3<64, 4><<<dim3(g2, 1), blk, 0, stream>>>(canvas, 84 * HW, b1w0, b1s0, b1t0,
                                                  s16a, 4 * HW, 2 * HW);
  conv3x3<4, 4><<<dim3(g2, 1), blk, 0, stream>>>(s16a, 4 * HW, b1w + 0 * 144,
                                                 b1s + 0, b1t + 0, s16b, 4 * HW,
                                                 2 * HW);
  conv3x3<4, 4><<<dim3(g2, 1), blk, 0, stream>>>(s16b, 4 * HW, b1w + 1 * 144,
                                                 b1s + 4, b1t + 4, s16a, 4 * HW,
                                                 2 * HW);
  conv3x3<4, 4><<<dim3(g2, 1), blk, 0, stream>>>(s16a, 4 * HW, b1w + 2 * 144,
                                                 b1s + 8, b1t + 8, out, 84 * HW,
                                                 2 * HW);

  // block2: 4->16, 5x(16->16); x2 -> out ch4..19
  conv3x3<4, 16><<<dim3(g2, 1), blk, 0, stream>>>(out, 84 * HW, b2w0, b2s0, b2t0,
                                                  s16a, 16 * HW, 2 * HW);
  conv3x3<16, 16><<<dim3(g2, 1), blk, 0, stream>>>(s16a, 16 * HW, b2w + 0 * 2304,
                                                   b2s + 0, b2t + 0, s16b, 16 * HW,
                                                   2 * HW);
  conv3x3<16, 16><<<dim3(g2, 1), blk, 0, stream>>>(s16b, 16 * HW, b2w + 1 * 2304,
                                                   b2s + 16, b2t + 16, s16a, 16 * HW,
                                                   2 * HW);
  conv3x3<16, 16><<<dim3(g2, 1), blk, 0, stream>>>(s16a, 16 * HW, b2w + 2 * 2304,
                                                   b2s + 32, b2t + 32, s16b, 16 * HW,
                                                   2 * HW);
  conv3x3<16, 16><<<dim3(g2, 1), blk, 0, stream>>>(s16b, 16 * HW, b2w + 3 * 2304,
                                                   b2s + 48, b2t + 48, s16a, 16 * HW,
                                                   2 * HW);
  conv3x3<16, 16><<<dim3(g2, 1), blk, 0, stream>>>(s16a, 16 * HW, b2w + 4 * 2304,
                                                   b2s + 64, b2t + 64, out + 4 * HW,
                                                   84 * HW, 2 * HW);

  // block3 via MFMA, BOTH batches per dispatch (grid.y = Bn).
  // n16/pong live in out ch20..83 of each batch (dead canvas; FINAL rewrites
  // as x3 fp32). ppA(b) at ws + b*64HW bf16. Layer l for both batches finishes
  // before layer l+1 starts (separate dispatches) -> same per-batch ordering.
  __bf16* n16 = (__bf16*)canvas;            // per-batch stride 84*HW*2 bf16 elems
  const size_t canv_s = (size_t)84 * HW * 2;
  const size_t ppa_s = (size_t)64 * HW;
  // input = x2 = out ch4..19
  cvt_nhwc16<<<(Bn * HW + 255) / 256, 256, 0, stream>>>(out + (size_t)4 * HW, n16);
  dim3 mg(31 * 27, Bn);  // 16x16-pixel tiles x batches
  mconv<16, false><<<mg, blk, 0, stream>>>(n16, canv_s, Wt, b3s0, b3t0, ppA, ppa_s,
                                           nullptr, 0);
  mconv<64, false><<<mg, blk, 0, stream>>>(ppA, ppa_s, Wt + 9216 + 0 * 36864,
                                           b3s + 0, b3t + 0, n16, canv_s, nullptr,
                                           0);
  mconv<64, false><<<mg, blk, 0, stream>>>(n16, canv_s, Wt + 9216 + 1 * 36864,
                                           b3s + 64, b3t + 64, ppA, ppa_s, nullptr,
                                           0);
  mconv<64, false><<<mg, blk, 0, stream>>>(ppA, ppa_s, Wt + 9216 + 2 * 36864,
                                           b3s + 128, b3t + 128, n16, canv_s,
                                           nullptr, 0);
  mconv<64, false><<<mg, blk, 0, stream>>>(n16, canv_s, Wt + 9216 + 3 * 36864,
                                           b3s + 192, b3t + 192, ppA, ppa_s,
                                           nullptr, 0);
  mconv<64, true><<<mg, blk, 0, stream>>>(ppA, ppa_s, Wt + 9216 + 4 * 36864,
                                          b3s + 256, b3t + 256, nullptr, 0, canvas,
                                          (size_t)84 * HW);
}